// Round 9
// baseline (371.191 us; speedup 1.0000x reference)
//
#include <hip/hip_runtime.h>

#define N_NODES    100000
#define N_EDGES    1600000
#define NUM_REL    4
#define NUM_GRAPHS 256

constexpr int NR       = N_NODES * NUM_REL;   // 400000 segments
constexpr int NB       = (NR + 255) / 256;    // 1563 scan blocks
constexpr int SB_ITEMS = (NB + 255) / 256;    // 7 items/thread in scanB
constexpr int NBUK     = N_NODES / 32;        // 3125 buckets (32 nodes = 128 segments each)

typedef _Float16 half4v __attribute__((ext_vector_type(4)));  // 8B
typedef _Float16 half8v __attribute__((ext_vector_type(8)));  // 16B
typedef float    f32x4  __attribute__((ext_vector_type(4)));

// ---- monotonic float<->uint encoding for atomicMax on floats ----
__device__ __forceinline__ unsigned fenc(float f) {
    unsigned u = __float_as_uint(f);
    return (u & 0x80000000u) ? ~u : (u | 0x80000000u);
}
__device__ __forceinline__ float fdec(unsigned e) {
    return __uint_as_float((e & 0x80000000u) ? (e ^ 0x80000000u) : ~e);
}

__device__ __forceinline__ void bstack_fill(const float* __restrict__ W,
                                            const float* __restrict__ root,
                                            _Float16* __restrict__ Bt,
                                            int i, int DIN, int DOUT, int SK) {
    int j = i / SK, kk = i % SK;
    float v = (kk < DIN) ? root[kk * DOUT + j]
            : (kk < 5 * DIN) ? W[(kk - DIN) * DOUT + j] : 0.f;
    Bt[j * SK + kk] = (_Float16)v;
}

// fused prep: zero cnt, init pool, fp16-convert x, build 3 weight stacks
__global__ void prep_kernel(const float* __restrict__ x, _Float16* __restrict__ xh,
                            const float* __restrict__ W1, const float* __restrict__ root1, _Float16* __restrict__ Bt1,
                            const float* __restrict__ W2, const float* __restrict__ root2, _Float16* __restrict__ Bt2,
                            const float* __restrict__ W3, const float* __restrict__ root3, _Float16* __restrict__ Bt3,
                            int* __restrict__ cnt, unsigned* __restrict__ pool) {
    int i = blockIdx.x * 256 + threadIdx.x;
    if (i < N_NODES * 16) xh[i] = (_Float16)x[i];
    if (i < NR) cnt[i] = 0;
    if (i < NUM_GRAPHS * 64) pool[i] = fenc(-INFINITY);
    if (i < 16 * 96)  bstack_fill(W1, root1, Bt1, i, 16, 16, 96);
    if (i < 32 * 96)  bstack_fill(W2, root2, Bt2, i, 16, 32, 96);
    if (i < 64 * 160) bstack_fill(W3, root3, Bt3, i, 32, 64, 160);
}

__global__ void count_kernel(const int* __restrict__ dst, const int* __restrict__ etype,
                             int* __restrict__ cnt) {
    int e = blockIdx.x * 256 + threadIdx.x;
    if (e >= N_EDGES) return;
    atomicAdd(cnt + dst[e] * NUM_REL + etype[e], 1);
}

__global__ void scanA_kernel(const int* __restrict__ cnt, int* __restrict__ incl,
                             int* __restrict__ bsums) {
    __shared__ int sd[256];
    int t = threadIdx.x;
    int idx = blockIdx.x * 256 + t;
    sd[t] = (idx < NR) ? cnt[idx] : 0;
    __syncthreads();
#pragma unroll
    for (int off = 1; off < 256; off <<= 1) {
        int a = (t >= off) ? sd[t - off] : 0;
        __syncthreads();
        sd[t] += a;
        __syncthreads();
    }
    if (idx < NR) incl[idx] = sd[t];
    if (t == 255) bsums[blockIdx.x] = sd[255];
}

__global__ void scanB_kernel(const int* __restrict__ bsums, int* __restrict__ boffs) {
    __shared__ int sd[256];
    int t = threadIdx.x;
    int pre[SB_ITEMS];
    int run = 0;
#pragma unroll
    for (int k = 0; k < SB_ITEMS; ++k) {
        int ix = t * SB_ITEMS + k;
        pre[k] = run;
        run += (ix < NB) ? bsums[ix] : 0;
    }
    sd[t] = run;
    __syncthreads();
#pragma unroll
    for (int off = 1; off < 256; off <<= 1) {
        int a = (t >= off) ? sd[t - off] : 0;
        __syncthreads();
        sd[t] += a;
        __syncthreads();
    }
    int excl = sd[t] - run;
#pragma unroll
    for (int k = 0; k < SB_ITEMS; ++k) {
        int ix = t * SB_ITEMS + k;
        if (ix < NB) boffs[ix] = excl + pre[k];
    }
}

// finalize exclusive offsets; also emit per-bucket cursors (bucket = 128 segments)
__global__ void scanC_kernel(const int* __restrict__ cnt, int* __restrict__ offs_inout,
                             const int* __restrict__ boffs, int* __restrict__ bcur) {
    int idx = blockIdx.x * 256 + threadIdx.x;
    if (idx >= NR) return;
    int e = boffs[idx >> 8] + offs_inout[idx] - cnt[idx];
    offs_inout[idx] = e;
    if ((idx & 127) == 0) bcur[idx >> 7] = e;
}

// phase 1: append (src, seg) pairs into per-bucket regions (dense writes)
__global__ void pairs_kernel(const int* __restrict__ src, const int* __restrict__ dst,
                             const int* __restrict__ etype, int* __restrict__ bcur,
                             uint2* __restrict__ pairs) {
    int e = blockIdx.x * 256 + threadIdx.x;
    if (e >= N_EDGES) return;
    int d = dst[e];
    int seg = d * NUM_REL + etype[e];
    int pos = atomicAdd(bcur + (d >> 5), 1);
    pairs[pos] = uint2{(unsigned)src[e], (unsigned)seg};
}

// phase 2: within-bucket scatter to final CSR slots (localized writes);
// offs[seg] ends at segment END afterwards (= start + cnt)
__global__ void scatter_kernel(const uint2* __restrict__ pairs, int* __restrict__ offs,
                               int* __restrict__ csr) {
    int e = blockIdx.x * 256 + threadIdx.x;
    if (e >= N_EDGES) return;
    uint2 p = pairs[e];
    int pos = atomicAdd(offs + p.y, 1);
    csr[pos] = p.x;
}

// gather-only: pre[n] = [ x_n (DIN) | mean_r0 .. mean_r3 (DIN each) | pad ]
// 4 lanes per (node,rel) segment; 16 nodes per block; no LDS, no barriers.
template<int DIN, int SK>
__global__ __launch_bounds__(256)
void gather_kernel(const _Float16* __restrict__ x,
                   const int* __restrict__ csr,
                   const int* __restrict__ offsets,   // segment ENDs
                   const int* __restrict__ cnt,
                   _Float16* __restrict__ pre) {
    constexpr int NPB = 16;
    constexpr int CPL = DIN / 4;     // fp16 channels per lane (4 or 8)
    using VecT = typename std::conditional<CPL == 8, half8v, half4v>::type;

    const int tid = threadIdx.x;
    const int g    = tid >> 2;       // 0..63 segment group
    const int q    = tid & 3;
    const int nsub = g >> 2;
    const int r    = g & 3;
    const int n    = blockIdx.x * NPB + nsub;
    const int seg  = n * NUM_REL + r;
    const int len  = cnt[seg];
    const int start = offsets[seg] - len;
    const VecT* xv = (const VecT*)x;     // row = 4 VecT

    float acc[CPL];
#pragma unroll
    for (int ch = 0; ch < CPL; ++ch) acc[ch] = 0.f;

    for (int k = 0; k < len; k += 8) {
        int lim = len - k;               // >= 1
        int c[8];
#pragma unroll
        for (int m = 0; m < 8; ++m)
            c[m] = csr[start + (m < lim ? k + m : k)];
        VecT u[8];
#pragma unroll
        for (int m = 0; m < 8; ++m)
            u[m] = xv[(size_t)c[m] * 4 + q];
#pragma unroll
        for (int m = 0; m < 8; ++m)
            if (m < lim) {
#pragma unroll
                for (int ch = 0; ch < CPL; ++ch) acc[ch] += (float)u[m][ch];
            }
    }
    float inv = 1.0f / fmaxf((float)len, 1.0f);
    VecT hv;
#pragma unroll
    for (int ch = 0; ch < CPL; ++ch) hv[ch] = (_Float16)(acc[ch] * inv);
    *(VecT*)&pre[(size_t)n * SK + DIN + r * DIN + q * CPL] = hv;
    if (r == 0)
        *(VecT*)&pre[(size_t)n * SK + q * CPL] = xv[(size_t)n * 4 + q];
    if constexpr (SK > 5 * DIN) {
        // zero the K-pad (SK - 5*DIN = 16 fp16 = 2x16B per node)
        if (tid < NPB * 2) {
            int n2 = blockIdx.x * NPB + (tid >> 1);
            *(uint4*)&pre[(size_t)n2 * SK + 5 * DIN + (tid & 1) * 8] = uint4{0, 0, 0, 0};
        }
    }
}

// MFMA GEMM: hout[N, DOUT] = relu(pre[N, K] @ Bstack[K, DOUT] + bias)
// fragment mapping (m89-verified): A: lane=[l&15][(l>>4)*8+u]; B: [k][l&15]; D: [(l>>4)*4+reg][l&15]
template<int K, int DOUT, bool RELU>
__global__ __launch_bounds__(256)
void gemm_kernel(const _Float16* __restrict__ pre,
                 const _Float16* __restrict__ Bt,    // [DOUT][K]
                 const float* __restrict__ bias,     // [DOUT]
                 _Float16* __restrict__ hout) {
    constexpr int NT = DOUT / 16;
    constexpr int KS = K / 32;
    constexpr int KP = K + 8;                        // LDS row pad: kill bank conflicts
    __shared__ _Float16 sB[DOUT * KP];
    for (int i = threadIdx.x; i < DOUT * K; i += 256) {
        int j = i / K, kk = i % K;
        sB[j * KP + kk] = Bt[i];
    }
    __syncthreads();

    const int w = threadIdx.x >> 6, lane = threadIdx.x & 63;
    const int m0 = (blockIdx.x * 4 + w) * 16;
    if (m0 >= N_NODES) return;
    const int lo16 = lane & 15, hi = lane >> 4;

    f32x4 acc[NT];
#pragma unroll
    for (int nt = 0; nt < NT; ++nt) acc[nt] = f32x4{0.f, 0.f, 0.f, 0.f};

#pragma unroll
    for (int ks = 0; ks < KS; ++ks) {
        half8v a = *(const half8v*)&pre[(size_t)(m0 + lo16) * K + ks * 32 + hi * 8];
#pragma unroll
        for (int nt = 0; nt < NT; ++nt) {
            half8v b = *(const half8v*)&sB[(nt * 16 + lo16) * KP + ks * 32 + hi * 8];
            acc[nt] = __builtin_amdgcn_mfma_f32_16x16x32_f16(a, b, acc[nt], 0, 0, 0);
        }
    }
#pragma unroll
    for (int nt = 0; nt < NT; ++nt) {
        float bj = bias[nt * 16 + lo16];
#pragma unroll
        for (int reg = 0; reg < 4; ++reg) {
            float v = acc[nt][reg] + bj;
            if (RELU) v = fmaxf(v, 0.f);
            hout[(size_t)(m0 + hi * 4 + reg) * DOUT + nt * 16 + lo16] = (_Float16)v;
        }
    }
}

// max-pool over sorted batch: each thread scans 64 nodes for one channel
__global__ __launch_bounds__(256)
void pool_kernel(const _Float16* __restrict__ h3, const int* __restrict__ batch,
                 unsigned* __restrict__ pool) {
    const int j = threadIdx.x & 63;
    const int grp = threadIdx.x >> 6;
    const int n0 = blockIdx.x * 256 + grp * 64;
    if (n0 >= N_NODES) return;
    const int end = min(n0 + 64, N_NODES);
    int g = batch[n0];
    float m = -INFINITY;
    for (int n = n0; n < end; ++n) {
        float v = (float)h3[(size_t)n * 64 + j];
        int bg = batch[n];
        if (bg != g) {
            atomicMax(pool + g * 64 + j, fenc(m));
            g = bg;
            m = v;
        } else {
            m = fmaxf(m, v);
        }
    }
    atomicMax(pool + g * 64 + j, fenc(m));
}

__global__ void decode_kernel(const unsigned* __restrict__ pool, float* __restrict__ out) {
    int i = blockIdx.x * blockDim.x + threadIdx.x;
    if (i < NUM_GRAPHS * 64) out[i] = fdec(pool[i]);
}

extern "C" void kernel_launch(void* const* d_in, const int* in_sizes, int n_in,
                              void* d_out, int out_size, void* d_ws, size_t ws_size,
                              hipStream_t stream) {
    const float* x     = (const float*)d_in[0];
    const int*   ei    = (const int*)d_in[1];
    const int*   etype = (const int*)d_in[2];
    const int*   batch = (const int*)d_in[3];
    const float* W1 = (const float*)d_in[4],  *root1 = (const float*)d_in[5],  *b1 = (const float*)d_in[6];
    const float* W2 = (const float*)d_in[7],  *root2 = (const float*)d_in[8],  *b2 = (const float*)d_in[9];
    const float* W3 = (const float*)d_in[10], *root3 = (const float*)d_in[11], *b3 = (const float*)d_in[12];
    float* out = (float*)d_out;

    const int* src = ei;
    const int* dst = ei + N_EDGES;

    // workspace layout (~67.6 MB), all sections 16B aligned
    int*       cnt   = (int*)d_ws;                     // NR
    int*       offs  = cnt + NR;                       // NR
    int*       bsums = offs + NR;                      // 2048
    int*       boffs = bsums + 2048;                   // 2048
    int*       bcur  = boffs + 2048;                   // NBUK (3125) -> pad 3200
    int*       csr   = bcur + 3200;                    // N_EDGES
    _Float16*  xh    = (_Float16*)(csr + N_EDGES);     // N*16
    _Float16*  h1    = xh + (size_t)N_NODES * 16;      // N*16
    _Float16*  h2    = h1 + (size_t)N_NODES * 16;      // N*32
    _Float16*  h3    = h2 + (size_t)N_NODES * 32;      // N*64
    _Float16*  pre   = h3 + (size_t)N_NODES * 64;      // N*160 (max)
    _Float16*  Bt1   = pre + (size_t)N_NODES * 160;    // 16*96
    _Float16*  Bt2   = Bt1 + 16 * 96;                  // 32*96
    _Float16*  Bt3   = Bt2 + 32 * 96;                  // 64*160
    unsigned*  pool  = (unsigned*)(Bt3 + 64 * 160);    // 256*64
    uint2*     pairs = (uint2*)pre;                    // aliases pre (used only pre-gather)

    const int BT = 256;
    const int gE = (N_EDGES + BT - 1) / BT;
    const int gI = (NR + BT - 1) / BT;
    const int gG = N_NODES / 16;            // gather blocks
    const int gM = (N_NODES / 16 + 3) / 4;  // gemm blocks (4 M-tiles each)

    prep_kernel<<<(N_NODES * 16 + BT - 1) / BT, BT, 0, stream>>>(
        x, xh, W1, root1, Bt1, W2, root2, Bt2, W3, root3, Bt3, cnt, pool);

    count_kernel<<<gE, BT, 0, stream>>>(dst, etype, cnt);
    scanA_kernel<<<NB, BT, 0, stream>>>(cnt, offs, bsums);
    scanB_kernel<<<1, BT, 0, stream>>>(bsums, boffs);
    scanC_kernel<<<gI, BT, 0, stream>>>(cnt, offs, boffs, bcur);
    pairs_kernel<<<gE, BT, 0, stream>>>(src, dst, etype, bcur, pairs);
    scatter_kernel<<<gE, BT, 0, stream>>>(pairs, offs, csr);

    gather_kernel<16, 96><<<gG, BT, 0, stream>>>(xh, csr, offs, cnt, pre);
    gemm_kernel<96, 16, true><<<gM, BT, 0, stream>>>(pre, Bt1, b1, h1);

    gather_kernel<16, 96><<<gG, BT, 0, stream>>>(h1, csr, offs, cnt, pre);
    gemm_kernel<96, 32, true><<<gM, BT, 0, stream>>>(pre, Bt2, b2, h2);

    gather_kernel<32, 160><<<gG, BT, 0, stream>>>(h2, csr, offs, cnt, pre);
    gemm_kernel<160, 64, false><<<gM, BT, 0, stream>>>(pre, Bt3, b3, h3);

    pool_kernel<<<(N_NODES + 255) / 256, BT, 0, stream>>>(h3, batch, pool);
    decode_kernel<<<(NUM_GRAPHS * 64 + BT - 1) / BT, BT, 0, stream>>>(pool, out);
}

// Round 10
// 181.701 us; speedup vs baseline: 2.0429x; 2.0429x over previous
//
#include <hip/hip_runtime.h>

#define N_NODES    100000
#define N_EDGES    1600000
#define NUM_REL    4
#define NUM_GRAPHS 256

constexpr int NR   = N_NODES * NUM_REL;       // 400000 segments
constexpr int NBK  = (N_NODES + 255) / 256;   // 391 buckets of 256 nodes (1024 segments)
constexpr int CHK  = 8192;                    // edges per binning block
constexpr int NCH  = (N_EDGES + CHK - 1) / CHK; // 196 chunks

typedef _Float16 half4v __attribute__((ext_vector_type(4)));  // 8B
typedef _Float16 half8v __attribute__((ext_vector_type(8)));  // 16B
typedef float    f32x4  __attribute__((ext_vector_type(4)));

// ---- monotonic float<->uint encoding for atomicMax on floats ----
__device__ __forceinline__ unsigned fenc(float f) {
    unsigned u = __float_as_uint(f);
    return (u & 0x80000000u) ? ~u : (u | 0x80000000u);
}
__device__ __forceinline__ float fdec(unsigned e) {
    return __uint_as_float((e & 0x80000000u) ? (e ^ 0x80000000u) : ~e);
}

__device__ __forceinline__ void bstack_fill(const float* __restrict__ W,
                                            const float* __restrict__ root,
                                            _Float16* __restrict__ Bt,
                                            int i, int DIN, int DOUT, int SK) {
    int j = i / SK, kk = i % SK;
    float v = (kk < DIN) ? root[kk * DOUT + j]
            : (kk < 5 * DIN) ? W[(kk - DIN) * DOUT + j] : 0.f;
    Bt[j * SK + kk] = (_Float16)v;
}

// fused prep: zero bucket counts, init pool, fp16-convert x, build 3 weight stacks
__global__ void prep_kernel(const float* __restrict__ x, _Float16* __restrict__ xh,
                            const float* __restrict__ W1, const float* __restrict__ root1, _Float16* __restrict__ Bt1,
                            const float* __restrict__ W2, const float* __restrict__ root2, _Float16* __restrict__ Bt2,
                            const float* __restrict__ W3, const float* __restrict__ root3, _Float16* __restrict__ Bt3,
                            int* __restrict__ bkcnt, unsigned* __restrict__ pool) {
    int i = blockIdx.x * 256 + threadIdx.x;
    if (i < N_NODES * 16) xh[i] = (_Float16)x[i];
    if (i < 512) bkcnt[i] = 0;
    if (i < NUM_GRAPHS * 64) pool[i] = fenc(-INFINITY);
    if (i < 16 * 96)  bstack_fill(W1, root1, Bt1, i, 16, 16, 96);
    if (i < 32 * 96)  bstack_fill(W2, root2, Bt2, i, 16, 32, 96);
    if (i < 64 * 160) bstack_fill(W3, root3, Bt3, i, 32, 64, 160);
}

// bucket histogram (LDS-aggregated)
__global__ __launch_bounds__(256)
void cbuck_kernel(const int* __restrict__ dst, int* __restrict__ bkcnt) {
    __shared__ int h[512];
    const int t = threadIdx.x;
    h[t] = 0; h[t + 256] = 0;
    __syncthreads();
    const int e0 = blockIdx.x * CHK;
#pragma unroll
    for (int k = 0; k < CHK / 256; ++k) {
        int e = e0 + k * 256 + t;
        if (e < N_EDGES) atomicAdd(&h[dst[e] >> 8], 1);
    }
    __syncthreads();
    for (int b = t; b < NBK; b += 256) {
        int v = h[b];
        if (v) atomicAdd(&bkcnt[b], v);
    }
}

// exclusive scan of bucket counts -> bucket bases (ebase) + append cursors (bcur)
__global__ void scanE_kernel(const int* __restrict__ bkcnt, int* __restrict__ ebase,
                             int* __restrict__ bcur) {
    __shared__ int sd[256];
    const int t = threadIdx.x;
    int a0 = (2 * t < NBK)     ? bkcnt[2 * t]     : 0;
    int a1 = (2 * t + 1 < NBK) ? bkcnt[2 * t + 1] : 0;
    int run = a0 + a1;
    sd[t] = run;
    __syncthreads();
#pragma unroll
    for (int off = 1; off < 256; off <<= 1) {
        int a = (t >= off) ? sd[t - off] : 0;
        __syncthreads();
        sd[t] += a;
        __syncthreads();
    }
    int excl = sd[t] - run;
    if (2 * t < NBK)     { ebase[2 * t] = excl;          bcur[2 * t] = excl; }
    if (2 * t + 1 < NBK) { ebase[2 * t + 1] = excl + a0; bcur[2 * t + 1] = excl + a0; }
}

// partition edges into bucket-contiguous packed pairs: (localseg<<17) | src
// block-local LDS histogram + one reservation per (block,bucket) -> dense writes
__global__ __launch_bounds__(256)
void bin_kernel(const int* __restrict__ src, const int* __restrict__ dst,
                const int* __restrict__ etype, int* __restrict__ bcur,
                unsigned* __restrict__ pairs) {
    __shared__ int h[512];
    __shared__ int base[512];
    const int t = threadIdx.x;
    h[t] = 0; h[t + 256] = 0;
    __syncthreads();
    const int e0 = blockIdx.x * CHK;
    int d[CHK / 256];
#pragma unroll
    for (int k = 0; k < CHK / 256; ++k) {
        int e = e0 + k * 256 + t;
        d[k] = (e < N_EDGES) ? dst[e] : -1;
        if (d[k] >= 0) atomicAdd(&h[d[k] >> 8], 1);
    }
    __syncthreads();
    for (int b = t; b < NBK; b += 256) {
        int v = h[b];
        base[b] = v ? atomicAdd(&bcur[b], v) : 0;
        h[b] = 0;
    }
    __syncthreads();
#pragma unroll
    for (int k = 0; k < CHK / 256; ++k) {
        if (d[k] < 0) continue;
        int e = e0 + k * 256 + t;
        int b = d[k] >> 8;
        int pos = base[b] + atomicAdd(&h[b], 1);
        unsigned ls = ((unsigned)(d[k] & 255) << 2) | (unsigned)etype[e];
        pairs[pos] = (unsigned)src[e] | (ls << 17);
    }
}

// per-bucket LDS counting sort: writes csr (bucket-local window) and cnt/offs
// for the bucket's 1024 segments (offs = segment END). Zero global atomics.
__global__ __launch_bounds__(256)
void sortseg_kernel(const unsigned* __restrict__ pairs, const int* __restrict__ ebase,
                    const int* __restrict__ bkcnt, int* __restrict__ csr,
                    int* __restrict__ cnt, int* __restrict__ offs) {
    __shared__ int hist[1024];
    __shared__ int sd[256];
    const int b = blockIdx.x;
    const int base = ebase[b];
    const int len  = bkcnt[b];
    const int t = threadIdx.x;
#pragma unroll
    for (int i = 0; i < 4; ++i) hist[t * 4 + i] = 0;
    __syncthreads();
    for (int i = t; i < len; i += 256)
        atomicAdd(&hist[pairs[base + i] >> 17], 1);
    __syncthreads();
    int c0 = hist[4 * t], c1 = hist[4 * t + 1], c2 = hist[4 * t + 2], c3 = hist[4 * t + 3];
    int run = c0 + c1 + c2 + c3;
    sd[t] = run;
    __syncthreads();
#pragma unroll
    for (int off = 1; off < 256; off <<= 1) {
        int a = (t >= off) ? sd[t - off] : 0;
        __syncthreads();
        sd[t] += a;
        __syncthreads();
    }
    int excl = sd[t] - run;
    int e0 = excl, e1 = excl + c0, e2 = excl + c0 + c1, e3 = excl + c0 + c1 + c2;
    hist[4 * t] = e0; hist[4 * t + 1] = e1; hist[4 * t + 2] = e2; hist[4 * t + 3] = e3;
    int seg0 = b * 1024 + 4 * t;
    if (seg0 < NR) {   // NR % 4 == 0 so the whole int4 is in range
        *(int4*)&cnt[seg0]  = int4{c0, c1, c2, c3};
        *(int4*)&offs[seg0] = int4{base + e0 + c0, base + e1 + c1,
                                   base + e2 + c2, base + e3 + c3};
    }
    __syncthreads();
    for (int i = t; i < len; i += 256) {
        unsigned p = pairs[base + i];
        int pos = atomicAdd(&hist[p >> 17], 1);   // LDS
        csr[base + pos] = (int)(p & 0x1FFFFu);
    }
}

// gather-only: pre[n] = [ x_n (DIN) | mean_r0 .. mean_r3 (DIN each) | pad ]
// 4 lanes per (node,rel) segment; 16 nodes per block; no LDS, no barriers.
template<int DIN, int SK>
__global__ __launch_bounds__(256)
void gather_kernel(const _Float16* __restrict__ x,
                   const int* __restrict__ csr,
                   const int* __restrict__ offsets,   // segment ENDs
                   const int* __restrict__ cnt,
                   _Float16* __restrict__ pre) {
    constexpr int NPB = 16;
    constexpr int CPL = DIN / 4;     // fp16 channels per lane (4 or 8)
    using VecT = typename std::conditional<CPL == 8, half8v, half4v>::type;

    const int tid = threadIdx.x;
    const int g    = tid >> 2;       // 0..63 segment group
    const int q    = tid & 3;
    const int nsub = g >> 2;
    const int r    = g & 3;
    const int n    = blockIdx.x * NPB + nsub;
    const int seg  = n * NUM_REL + r;
    const int len  = cnt[seg];
    const int start = offsets[seg] - len;
    const VecT* xv = (const VecT*)x;     // row = 4 VecT

    float acc[CPL];
#pragma unroll
    for (int ch = 0; ch < CPL; ++ch) acc[ch] = 0.f;

    for (int k = 0; k < len; k += 8) {
        int lim = len - k;               // >= 1
        int c[8];
#pragma unroll
        for (int m = 0; m < 8; ++m)
            c[m] = csr[start + (m < lim ? k + m : k)];
        VecT u[8];
#pragma unroll
        for (int m = 0; m < 8; ++m)
            u[m] = xv[(size_t)c[m] * 4 + q];
#pragma unroll
        for (int m = 0; m < 8; ++m)
            if (m < lim) {
#pragma unroll
                for (int ch = 0; ch < CPL; ++ch) acc[ch] += (float)u[m][ch];
            }
    }
    float inv = 1.0f / fmaxf((float)len, 1.0f);
    VecT hv;
#pragma unroll
    for (int ch = 0; ch < CPL; ++ch) hv[ch] = (_Float16)(acc[ch] * inv);
    *(VecT*)&pre[(size_t)n * SK + DIN + r * DIN + q * CPL] = hv;
    if (r == 0)
        *(VecT*)&pre[(size_t)n * SK + q * CPL] = xv[(size_t)n * 4 + q];
    if constexpr (SK > 5 * DIN) {
        if (tid < NPB * 2) {
            int n2 = blockIdx.x * NPB + (tid >> 1);
            *(uint4*)&pre[(size_t)n2 * SK + 5 * DIN + (tid & 1) * 8] = uint4{0, 0, 0, 0};
        }
    }
}

// MFMA GEMM: hout[N, DOUT] = relu(pre[N, K] @ Bstack[K, DOUT] + bias)
template<int K, int DOUT, bool RELU>
__global__ __launch_bounds__(256)
void gemm_kernel(const _Float16* __restrict__ pre,
                 const _Float16* __restrict__ Bt,    // [DOUT][K]
                 const float* __restrict__ bias,     // [DOUT]
                 _Float16* __restrict__ hout) {
    constexpr int NT = DOUT / 16;
    constexpr int KS = K / 32;
    constexpr int KP = K + 8;                        // LDS row pad
    __shared__ _Float16 sB[DOUT * KP];
    for (int i = threadIdx.x; i < DOUT * K; i += 256) {
        int j = i / K, kk = i % K;
        sB[j * KP + kk] = Bt[i];
    }
    __syncthreads();

    const int w = threadIdx.x >> 6, lane = threadIdx.x & 63;
    const int m0 = (blockIdx.x * 4 + w) * 16;
    if (m0 >= N_NODES) return;
    const int lo16 = lane & 15, hi = lane >> 4;

    f32x4 acc[NT];
#pragma unroll
    for (int nt = 0; nt < NT; ++nt) acc[nt] = f32x4{0.f, 0.f, 0.f, 0.f};

#pragma unroll
    for (int ks = 0; ks < KS; ++ks) {
        half8v a = *(const half8v*)&pre[(size_t)(m0 + lo16) * K + ks * 32 + hi * 8];
#pragma unroll
        for (int nt = 0; nt < NT; ++nt) {
            half8v b = *(const half8v*)&sB[(nt * 16 + lo16) * KP + ks * 32 + hi * 8];
            acc[nt] = __builtin_amdgcn_mfma_f32_16x16x32_f16(a, b, acc[nt], 0, 0, 0);
        }
    }
#pragma unroll
    for (int nt = 0; nt < NT; ++nt) {
        float bj = bias[nt * 16 + lo16];
#pragma unroll
        for (int reg = 0; reg < 4; ++reg) {
            float v = acc[nt][reg] + bj;
            if (RELU) v = fmaxf(v, 0.f);
            hout[(size_t)(m0 + hi * 4 + reg) * DOUT + nt * 16 + lo16] = (_Float16)v;
        }
    }
}

// max-pool over sorted batch: each thread scans 64 nodes for one channel
__global__ __launch_bounds__(256)
void pool_kernel(const _Float16* __restrict__ h3, const int* __restrict__ batch,
                 unsigned* __restrict__ pool) {
    const int j = threadIdx.x & 63;
    const int grp = threadIdx.x >> 6;
    const int n0 = blockIdx.x * 256 + grp * 64;
    if (n0 >= N_NODES) return;
    const int end = min(n0 + 64, N_NODES);
    int g = batch[n0];
    float m = -INFINITY;
    for (int n = n0; n < end; ++n) {
        float v = (float)h3[(size_t)n * 64 + j];
        int bg = batch[n];
        if (bg != g) {
            atomicMax(pool + g * 64 + j, fenc(m));
            g = bg;
            m = v;
        } else {
            m = fmaxf(m, v);
        }
    }
    atomicMax(pool + g * 64 + j, fenc(m));
}

__global__ void decode_kernel(const unsigned* __restrict__ pool, float* __restrict__ out) {
    int i = blockIdx.x * blockDim.x + threadIdx.x;
    if (i < NUM_GRAPHS * 64) out[i] = fdec(pool[i]);
}

extern "C" void kernel_launch(void* const* d_in, const int* in_sizes, int n_in,
                              void* d_out, int out_size, void* d_ws, size_t ws_size,
                              hipStream_t stream) {
    const float* x     = (const float*)d_in[0];
    const int*   ei    = (const int*)d_in[1];
    const int*   etype = (const int*)d_in[2];
    const int*   batch = (const int*)d_in[3];
    const float* W1 = (const float*)d_in[4],  *root1 = (const float*)d_in[5],  *b1 = (const float*)d_in[6];
    const float* W2 = (const float*)d_in[7],  *root2 = (const float*)d_in[8],  *b2 = (const float*)d_in[9];
    const float* W3 = (const float*)d_in[10], *root3 = (const float*)d_in[11], *b3 = (const float*)d_in[12];
    float* out = (float*)d_out;

    const int* src = ei;
    const int* dst = ei + N_EDGES;

    // workspace layout (~67 MB), all sections 16B aligned
    int*       cnt   = (int*)d_ws;                     // NR
    int*       offs  = cnt + NR;                       // NR
    int*       bkcnt = offs + NR;                      // 512
    int*       ebase = bkcnt + 512;                    // 512
    int*       bcur  = ebase + 512;                    // 512
    int*       csr   = bcur + 512;                     // N_EDGES
    _Float16*  xh    = (_Float16*)(csr + N_EDGES);     // N*16
    _Float16*  h1    = xh + (size_t)N_NODES * 16;      // N*16
    _Float16*  h2    = h1 + (size_t)N_NODES * 16;      // N*32
    _Float16*  h3    = h2 + (size_t)N_NODES * 32;      // N*64
    _Float16*  pre   = h3 + (size_t)N_NODES * 64;      // N*160 (max)
    _Float16*  Bt1   = pre + (size_t)N_NODES * 160;    // 16*96
    _Float16*  Bt2   = Bt1 + 16 * 96;                  // 32*96
    _Float16*  Bt3   = Bt2 + 32 * 96;                  // 64*160
    unsigned*  pool  = (unsigned*)(Bt3 + 64 * 160);    // 256*64
    unsigned*  pairs = (unsigned*)pre;                 // aliases pre (used only pre-gather)

    const int BT = 256;
    const int gG = N_NODES / 16;            // gather blocks
    const int gM = (N_NODES / 16 + 3) / 4;  // gemm blocks (4 M-tiles each)

    prep_kernel<<<(N_NODES * 16 + BT - 1) / BT, BT, 0, stream>>>(
        x, xh, W1, root1, Bt1, W2, root2, Bt2, W3, root3, Bt3, bkcnt, pool);

    cbuck_kernel<<<NCH, BT, 0, stream>>>(dst, bkcnt);
    scanE_kernel<<<1, BT, 0, stream>>>(bkcnt, ebase, bcur);
    bin_kernel<<<NCH, BT, 0, stream>>>(src, dst, etype, bcur, pairs);
    sortseg_kernel<<<NBK, BT, 0, stream>>>(pairs, ebase, bkcnt, csr, cnt, offs);

    gather_kernel<16, 96><<<gG, BT, 0, stream>>>(xh, csr, offs, cnt, pre);
    gemm_kernel<96, 16, true><<<gM, BT, 0, stream>>>(pre, Bt1, b1, h1);

    gather_kernel<16, 96><<<gG, BT, 0, stream>>>(h1, csr, offs, cnt, pre);
    gemm_kernel<96, 32, true><<<gM, BT, 0, stream>>>(pre, Bt2, b2, h2);

    gather_kernel<32, 160><<<gG, BT, 0, stream>>>(h2, csr, offs, cnt, pre);
    gemm_kernel<160, 64, false><<<gM, BT, 0, stream>>>(pre, Bt3, b3, h3);

    pool_kernel<<<(N_NODES + 255) / 256, BT, 0, stream>>>(h3, batch, pool);
    decode_kernel<<<(NUM_GRAPHS * 64 + BT - 1) / BT, BT, 0, stream>>>(pool, out);
}

// Round 11
// 140.000 us; speedup vs baseline: 2.6514x; 1.2979x over previous
//
#include <hip/hip_runtime.h>
#include <type_traits>

#define N_NODES    100000
#define N_EDGES    1600000
#define NUM_REL    4
#define NUM_GRAPHS 256

constexpr int NR   = N_NODES * NUM_REL;       // 400000 segments
constexpr int NBK  = (N_NODES + 255) / 256;   // 391 buckets of 256 nodes (1024 segments)
constexpr int CHK  = 8192;                    // edges per binning block
constexpr int NCH  = (N_EDGES + CHK - 1) / CHK; // 196 chunks

typedef _Float16 half4v __attribute__((ext_vector_type(4)));  // 8B
typedef _Float16 half8v __attribute__((ext_vector_type(8)));  // 16B
typedef float    f32x4  __attribute__((ext_vector_type(4)));

// ---- monotonic float<->uint encoding for atomicMax on floats ----
__device__ __forceinline__ unsigned fenc(float f) {
    unsigned u = __float_as_uint(f);
    return (u & 0x80000000u) ? ~u : (u | 0x80000000u);
}
__device__ __forceinline__ float fdec(unsigned e) {
    return __uint_as_float((e & 0x80000000u) ? (e ^ 0x80000000u) : ~e);
}

__device__ __forceinline__ void bstack_fill(const float* __restrict__ W,
                                            const float* __restrict__ root,
                                            _Float16* __restrict__ Bt,
                                            int i, int DIN, int DOUT, int SK) {
    int j = i / SK, kk = i % SK;
    float v = (kk < DIN) ? root[kk * DOUT + j]
            : (kk < 5 * DIN) ? W[(kk - DIN) * DOUT + j] : 0.f;
    Bt[j * SK + kk] = (_Float16)v;
}

// fused prep: zero bucket counts, init pool, fp16-convert x, build 3 weight stacks
__global__ void prep_kernel(const float* __restrict__ x, _Float16* __restrict__ xh,
                            const float* __restrict__ W1, const float* __restrict__ root1, _Float16* __restrict__ Bt1,
                            const float* __restrict__ W2, const float* __restrict__ root2, _Float16* __restrict__ Bt2,
                            const float* __restrict__ W3, const float* __restrict__ root3, _Float16* __restrict__ Bt3,
                            int* __restrict__ bkcnt, unsigned* __restrict__ pool) {
    int i = blockIdx.x * 256 + threadIdx.x;
    if (i < N_NODES * 16) xh[i] = (_Float16)x[i];
    if (i < 512) bkcnt[i] = 0;
    if (i < NUM_GRAPHS * 64) pool[i] = fenc(-INFINITY);
    if (i < 16 * 96)  bstack_fill(W1, root1, Bt1, i, 16, 16, 96);
    if (i < 32 * 96)  bstack_fill(W2, root2, Bt2, i, 16, 32, 96);
    if (i < 64 * 160) bstack_fill(W3, root3, Bt3, i, 32, 64, 160);
}

// bucket histogram (LDS-aggregated)
__global__ __launch_bounds__(256)
void cbuck_kernel(const int* __restrict__ dst, int* __restrict__ bkcnt) {
    __shared__ int h[512];
    const int t = threadIdx.x;
    h[t] = 0; h[t + 256] = 0;
    __syncthreads();
    const int e0 = blockIdx.x * CHK;
#pragma unroll
    for (int k = 0; k < CHK / 256; ++k) {
        int e = e0 + k * 256 + t;
        if (e < N_EDGES) atomicAdd(&h[dst[e] >> 8], 1);
    }
    __syncthreads();
    for (int b = t; b < NBK; b += 256) {
        int v = h[b];
        if (v) atomicAdd(&bkcnt[b], v);
    }
}

// exclusive scan of bucket counts -> bucket bases (ebase) + append cursors (bcur)
__global__ void scanE_kernel(const int* __restrict__ bkcnt, int* __restrict__ ebase,
                             int* __restrict__ bcur) {
    __shared__ int sd[256];
    const int t = threadIdx.x;
    int a0 = (2 * t < NBK)     ? bkcnt[2 * t]     : 0;
    int a1 = (2 * t + 1 < NBK) ? bkcnt[2 * t + 1] : 0;
    int run = a0 + a1;
    sd[t] = run;
    __syncthreads();
#pragma unroll
    for (int off = 1; off < 256; off <<= 1) {
        int a = (t >= off) ? sd[t - off] : 0;
        __syncthreads();
        sd[t] += a;
        __syncthreads();
    }
    int excl = sd[t] - run;
    if (2 * t < NBK)     { ebase[2 * t] = excl;          bcur[2 * t] = excl; }
    if (2 * t + 1 < NBK) { ebase[2 * t + 1] = excl + a0; bcur[2 * t + 1] = excl + a0; }
}

// partition edges into bucket-contiguous packed pairs: (localseg<<17) | src
__global__ __launch_bounds__(256)
void bin_kernel(const int* __restrict__ src, const int* __restrict__ dst,
                const int* __restrict__ etype, int* __restrict__ bcur,
                unsigned* __restrict__ pairs) {
    __shared__ int h[512];
    __shared__ int base[512];
    const int t = threadIdx.x;
    h[t] = 0; h[t + 256] = 0;
    __syncthreads();
    const int e0 = blockIdx.x * CHK;
    int d[CHK / 256];
#pragma unroll
    for (int k = 0; k < CHK / 256; ++k) {
        int e = e0 + k * 256 + t;
        d[k] = (e < N_EDGES) ? dst[e] : -1;
        if (d[k] >= 0) atomicAdd(&h[d[k] >> 8], 1);
    }
    __syncthreads();
    for (int b = t; b < NBK; b += 256) {
        int v = h[b];
        base[b] = v ? atomicAdd(&bcur[b], v) : 0;
        h[b] = 0;
    }
    __syncthreads();
#pragma unroll
    for (int k = 0; k < CHK / 256; ++k) {
        if (d[k] < 0) continue;
        int e = e0 + k * 256 + t;
        int b = d[k] >> 8;
        int pos = base[b] + atomicAdd(&h[b], 1);
        unsigned ls = ((unsigned)(d[k] & 255) << 2) | (unsigned)etype[e];
        pairs[pos] = (unsigned)src[e] | (ls << 17);
    }
}

// per-bucket LDS counting sort: writes csr + cnt/offs (offs = segment END)
__global__ __launch_bounds__(256)
void sortseg_kernel(const unsigned* __restrict__ pairs, const int* __restrict__ ebase,
                    const int* __restrict__ bkcnt, int* __restrict__ csr,
                    int* __restrict__ cnt, int* __restrict__ offs) {
    __shared__ int hist[1024];
    __shared__ int sd[256];
    const int b = blockIdx.x;
    const int base = ebase[b];
    const int len  = bkcnt[b];
    const int t = threadIdx.x;
#pragma unroll
    for (int i = 0; i < 4; ++i) hist[t * 4 + i] = 0;
    __syncthreads();
    for (int i = t; i < len; i += 256)
        atomicAdd(&hist[pairs[base + i] >> 17], 1);
    __syncthreads();
    int c0 = hist[4 * t], c1 = hist[4 * t + 1], c2 = hist[4 * t + 2], c3 = hist[4 * t + 3];
    int run = c0 + c1 + c2 + c3;
    sd[t] = run;
    __syncthreads();
#pragma unroll
    for (int off = 1; off < 256; off <<= 1) {
        int a = (t >= off) ? sd[t - off] : 0;
        __syncthreads();
        sd[t] += a;
        __syncthreads();
    }
    int excl = sd[t] - run;
    int e0 = excl, e1 = excl + c0, e2 = excl + c0 + c1, e3 = excl + c0 + c1 + c2;
    hist[4 * t] = e0; hist[4 * t + 1] = e1; hist[4 * t + 2] = e2; hist[4 * t + 3] = e3;
    int seg0 = b * 1024 + 4 * t;
    if (seg0 < NR) {
        *(int4*)&cnt[seg0]  = int4{c0, c1, c2, c3};
        *(int4*)&offs[seg0] = int4{base + e0 + c0, base + e1 + c1,
                                   base + e2 + c2, base + e3 + c3};
    }
    __syncthreads();
    for (int i = t; i < len; i += 256) {
        unsigned p = pairs[base + i];
        int pos = atomicAdd(&hist[p >> 17], 1);   // LDS
        csr[base + pos] = (int)(p & 0x1FFFFu);
    }
}

// fused layer: gather (4 lanes/segment, 8-way ILP) -> LDS A-tile -> MFMA -> h/pool.
// A row n: [ x_n | mean_r0..r3 | zero pad to SK ], KP=SK+8 pad kills LDS bank conflicts.
// B fragments read directly from global weight stack (L1-resident).
template<int DIN, int DOUT, bool RELU, bool POOL>
__global__ __launch_bounds__(256)
void layer_kernel(const _Float16* __restrict__ x,
                  const int* __restrict__ csr,
                  const int* __restrict__ offsets,   // segment ENDs
                  const int* __restrict__ cnt,
                  const _Float16* __restrict__ Bt,   // [DOUT][SK]
                  const float* __restrict__ bias,    // [DOUT]
                  _Float16* __restrict__ hout,       // [N, DOUT] if !POOL
                  const int* __restrict__ batch,
                  unsigned* __restrict__ pool) {
    constexpr int SK  = (DIN == 16) ? 96 : 160;
    constexpr int KP  = SK + 8;      // fp16 pad -> row stride 208/336B (mod-32-dw = 20)
    constexpr int NPB = 16;
    constexpr int CPL = DIN / 4;     // fp16 channels per lane (4 or 8)
    constexpr int KS  = SK / 32;
    using VecT = typename std::conditional<CPL == 8, half8v, half4v>::type;

    __shared__ _Float16 sA[NPB][KP];
    __shared__ float pval[POOL ? NPB : 1][POOL ? 64 : 1];
    __shared__ int   pg[NPB];

    const int tid = threadIdx.x;

    // ---- gather into LDS ----
    {
        const int g    = tid >> 2;   // 0..63 segment group
        const int q    = tid & 3;
        const int nsub = g >> 2;
        const int r    = g & 3;
        const int n    = blockIdx.x * NPB + nsub;
        const int seg  = n * NUM_REL + r;
        const int len  = cnt[seg];
        const int start = offsets[seg] - len;
        const VecT* xv = (const VecT*)x;     // row = 4 VecT

        float acc[CPL];
#pragma unroll
        for (int ch = 0; ch < CPL; ++ch) acc[ch] = 0.f;

        for (int k = 0; k < len; k += 8) {
            int lim = len - k;               // >= 1
            int c[8];
#pragma unroll
            for (int m = 0; m < 8; ++m)
                c[m] = csr[start + (m < lim ? k + m : k)];
            VecT u[8];
#pragma unroll
            for (int m = 0; m < 8; ++m)
                u[m] = xv[(size_t)c[m] * 4 + q];
#pragma unroll
            for (int m = 0; m < 8; ++m)
                if (m < lim) {
#pragma unroll
                    for (int ch = 0; ch < CPL; ++ch) acc[ch] += (float)u[m][ch];
                }
        }
        float inv = 1.0f / fmaxf((float)len, 1.0f);
        VecT hv;
#pragma unroll
        for (int ch = 0; ch < CPL; ++ch) hv[ch] = (_Float16)(acc[ch] * inv);
        *(VecT*)&sA[nsub][DIN + r * DIN + q * CPL] = hv;
        if (r == 0)
            *(VecT*)&sA[nsub][q * CPL] = xv[(size_t)n * 4 + q];
        if constexpr (SK > 5 * DIN) {
            // zero K-pad cols [5*DIN, SK) = 16 fp16
            if (r == 1 && q < 2)
                *(uint4*)&sA[nsub][5 * DIN + q * 8] = uint4{0, 0, 0, 0};
        }
        if constexpr (POOL) {
            if (tid < NPB) pg[tid] = batch[blockIdx.x * NPB + tid];
        }
    }
    __syncthreads();

    // ---- MFMA: wave w computes output j-tile w (16 cols) for all 16 rows ----
    const int w = tid >> 6, lane = tid & 63;
    const int lo16 = lane & 15, hi = lane >> 4;
    if (w * 16 < DOUT) {
        const int jt = w;
        f32x4 acc = f32x4{0.f, 0.f, 0.f, 0.f};
#pragma unroll
        for (int ks = 0; ks < KS; ++ks) {
            half8v a = *(const half8v*)&sA[lo16][ks * 32 + hi * 8];
            half8v b = *(const half8v*)&Bt[(size_t)(jt * 16 + lo16) * SK + ks * 32 + hi * 8];
            acc = __builtin_amdgcn_mfma_f32_16x16x32_f16(a, b, acc, 0, 0, 0);
        }
        float bj = bias[jt * 16 + lo16];
#pragma unroll
        for (int reg = 0; reg < 4; ++reg) {
            float v = acc[reg] + bj;
            if (RELU) v = fmaxf(v, 0.f);
            if constexpr (POOL) {
                pval[hi * 4 + reg][jt * 16 + lo16] = v;
            } else {
                hout[(size_t)(blockIdx.x * NPB + hi * 4 + reg) * DOUT + jt * 16 + lo16] = (_Float16)v;
            }
        }
    }

    // ---- fused max-pool over the block's 16 (sorted-batch) nodes ----
    if constexpr (POOL) {
        __syncthreads();
        if (tid < 64) {
            const int j = tid;
            float m = pval[0][j];
            int g0 = pg[0];
#pragma unroll
            for (int i = 1; i < NPB; ++i) {
                if (pg[i] == g0) {
                    m = fmaxf(m, pval[i][j]);
                } else {
                    atomicMax(pool + g0 * 64 + j, fenc(m));
                    g0 = pg[i];
                    m = pval[i][j];
                }
            }
            atomicMax(pool + g0 * 64 + j, fenc(m));
        }
    }
}

__global__ void decode_kernel(const unsigned* __restrict__ pool, float* __restrict__ out) {
    int i = blockIdx.x * blockDim.x + threadIdx.x;
    if (i < NUM_GRAPHS * 64) out[i] = fdec(pool[i]);
}

extern "C" void kernel_launch(void* const* d_in, const int* in_sizes, int n_in,
                              void* d_out, int out_size, void* d_ws, size_t ws_size,
                              hipStream_t stream) {
    const float* x     = (const float*)d_in[0];
    const int*   ei    = (const int*)d_in[1];
    const int*   etype = (const int*)d_in[2];
    const int*   batch = (const int*)d_in[3];
    const float* W1 = (const float*)d_in[4],  *root1 = (const float*)d_in[5],  *b1 = (const float*)d_in[6];
    const float* W2 = (const float*)d_in[7],  *root2 = (const float*)d_in[8],  *b2 = (const float*)d_in[9];
    const float* W3 = (const float*)d_in[10], *root3 = (const float*)d_in[11], *b3 = (const float*)d_in[12];
    float* out = (float*)d_out;

    const int* src = ei;
    const int* dst = ei + N_EDGES;

    // workspace layout (~30 MB), all sections 16B aligned
    int*       cnt   = (int*)d_ws;                     // NR
    int*       offs  = cnt + NR;                       // NR
    int*       bkcnt = offs + NR;                      // 512
    int*       ebase = bkcnt + 512;                    // 512
    int*       bcur  = ebase + 512;                    // 512
    int*       csr   = bcur + 512;                     // N_EDGES
    unsigned*  pairs = (unsigned*)(csr + N_EDGES);     // N_EDGES
    _Float16*  xh    = (_Float16*)(pairs + N_EDGES);   // N*16
    _Float16*  h1    = xh + (size_t)N_NODES * 16;      // N*16
    _Float16*  h2    = h1 + (size_t)N_NODES * 16;      // N*32
    _Float16*  Bt1   = h2 + (size_t)N_NODES * 32;      // 16*96
    _Float16*  Bt2   = Bt1 + 16 * 96;                  // 32*96
    _Float16*  Bt3   = Bt2 + 32 * 96;                  // 64*160
    unsigned*  pool  = (unsigned*)(Bt3 + 64 * 160);    // 256*64

    const int BT = 256;
    const int gL = N_NODES / 16;            // fused layer blocks

    prep_kernel<<<(N_NODES * 16 + BT - 1) / BT, BT, 0, stream>>>(
        x, xh, W1, root1, Bt1, W2, root2, Bt2, W3, root3, Bt3, bkcnt, pool);

    cbuck_kernel<<<NCH, BT, 0, stream>>>(dst, bkcnt);
    scanE_kernel<<<1, BT, 0, stream>>>(bkcnt, ebase, bcur);
    bin_kernel<<<NCH, BT, 0, stream>>>(src, dst, etype, bcur, pairs);
    sortseg_kernel<<<NBK, BT, 0, stream>>>(pairs, ebase, bkcnt, csr, cnt, offs);

    layer_kernel<16, 16, true,  false><<<gL, BT, 0, stream>>>(
        xh, csr, offs, cnt, Bt1, b1, h1, batch, pool);
    layer_kernel<16, 32, true,  false><<<gL, BT, 0, stream>>>(
        h1, csr, offs, cnt, Bt2, b2, h2, batch, pool);
    layer_kernel<32, 64, false, true ><<<gL, BT, 0, stream>>>(
        h2, csr, offs, cnt, Bt3, b3, nullptr, batch, pool);

    decode_kernel<<<(NUM_GRAPHS * 64 + BT - 1) / BT, BT, 0, stream>>>(pool, out);
}

// Round 12
// 131.507 us; speedup vs baseline: 2.8226x; 1.0646x over previous
//
#include <hip/hip_runtime.h>
#include <type_traits>

#define N_NODES    100000
#define N_EDGES    1600000
#define NUM_REL    4
#define NUM_GRAPHS 256

constexpr int NR   = N_NODES * NUM_REL;       // 400000 segments
constexpr int NBK  = (N_NODES + 255) / 256;   // 391 buckets of 256 nodes (1024 segments)
constexpr int CHK  = 8192;                    // edges per binning block
constexpr int NCH  = (N_EDGES + CHK - 1) / CHK; // 196 chunks

typedef _Float16 half2v __attribute__((ext_vector_type(2)));  // 4B, v_pk_add_f16
typedef _Float16 half4v __attribute__((ext_vector_type(4)));  // 8B
typedef _Float16 half8v __attribute__((ext_vector_type(8)));  // 16B
typedef float    f32x4  __attribute__((ext_vector_type(4)));

// ---- monotonic float<->uint encoding for atomicMax on floats ----
__device__ __forceinline__ unsigned fenc(float f) {
    unsigned u = __float_as_uint(f);
    return (u & 0x80000000u) ? ~u : (u | 0x80000000u);
}
__device__ __forceinline__ float fdec(unsigned e) {
    return __uint_as_float((e & 0x80000000u) ? (e ^ 0x80000000u) : ~e);
}

__device__ __forceinline__ void bstack_fill(const float* __restrict__ W,
                                            const float* __restrict__ root,
                                            _Float16* __restrict__ Bt,
                                            int i, int DIN, int DOUT, int SK) {
    int j = i / SK, kk = i % SK;
    float v = (kk < DIN) ? root[kk * DOUT + j]
            : (kk < 5 * DIN) ? W[(kk - DIN) * DOUT + j] : 0.f;
    Bt[j * SK + kk] = (_Float16)v;
}

// fused prep: zero bucket counts, init pool, fp16-convert x, zero-rows, weight stacks
__global__ void prep_kernel(const float* __restrict__ x, _Float16* __restrict__ xh,
                            const float* __restrict__ W1, const float* __restrict__ root1, _Float16* __restrict__ Bt1,
                            const float* __restrict__ W2, const float* __restrict__ root2, _Float16* __restrict__ Bt2,
                            const float* __restrict__ W3, const float* __restrict__ root3, _Float16* __restrict__ Bt3,
                            int* __restrict__ bkcnt, unsigned* __restrict__ pool,
                            _Float16* __restrict__ h1, _Float16* __restrict__ h2) {
    int i = blockIdx.x * 256 + threadIdx.x;
    if (i < N_NODES * 16) xh[i] = (_Float16)x[i];
    if (i < 512) bkcnt[i] = 0;
    if (i < NUM_GRAPHS * 64) pool[i] = fenc(-INFINITY);
    if (i < 16 * 96)  bstack_fill(W1, root1, Bt1, i, 16, 16, 96);
    if (i < 32 * 96)  bstack_fill(W2, root2, Bt2, i, 16, 32, 96);
    if (i < 64 * 160) bstack_fill(W3, root3, Bt3, i, 32, 64, 160);
    // zero row N of each feature table (tail-lane target)
    if (i < 16) xh[(size_t)N_NODES * 16 + i] = (_Float16)0.f;
    if (i < 16) h1[(size_t)N_NODES * 16 + i] = (_Float16)0.f;
    if (i < 32) h2[(size_t)N_NODES * 32 + i] = (_Float16)0.f;
}

// bucket histogram (LDS-aggregated)
__global__ __launch_bounds__(256)
void cbuck_kernel(const int* __restrict__ dst, int* __restrict__ bkcnt) {
    __shared__ int h[512];
    const int t = threadIdx.x;
    h[t] = 0; h[t + 256] = 0;
    __syncthreads();
    const int e0 = blockIdx.x * CHK;
#pragma unroll
    for (int k = 0; k < CHK / 256; ++k) {
        int e = e0 + k * 256 + t;
        if (e < N_EDGES) atomicAdd(&h[dst[e] >> 8], 1);
    }
    __syncthreads();
    for (int b = t; b < NBK; b += 256) {
        int v = h[b];
        if (v) atomicAdd(&bkcnt[b], v);
    }
}

// exclusive scan of bucket counts -> bucket bases (ebase) + append cursors (bcur)
__global__ void scanE_kernel(const int* __restrict__ bkcnt, int* __restrict__ ebase,
                             int* __restrict__ bcur) {
    __shared__ int sd[256];
    const int t = threadIdx.x;
    int a0 = (2 * t < NBK)     ? bkcnt[2 * t]     : 0;
    int a1 = (2 * t + 1 < NBK) ? bkcnt[2 * t + 1] : 0;
    int run = a0 + a1;
    sd[t] = run;
    __syncthreads();
#pragma unroll
    for (int off = 1; off < 256; off <<= 1) {
        int a = (t >= off) ? sd[t - off] : 0;
        __syncthreads();
        sd[t] += a;
        __syncthreads();
    }
    int excl = sd[t] - run;
    if (2 * t < NBK)     { ebase[2 * t] = excl;          bcur[2 * t] = excl; }
    if (2 * t + 1 < NBK) { ebase[2 * t + 1] = excl + a0; bcur[2 * t + 1] = excl + a0; }
}

// partition edges into bucket-contiguous packed pairs: (localseg<<17) | src
__global__ __launch_bounds__(256)
void bin_kernel(const int* __restrict__ src, const int* __restrict__ dst,
                const int* __restrict__ etype, int* __restrict__ bcur,
                unsigned* __restrict__ pairs) {
    __shared__ int h[512];
    __shared__ int base[512];
    const int t = threadIdx.x;
    h[t] = 0; h[t + 256] = 0;
    __syncthreads();
    const int e0 = blockIdx.x * CHK;
    int d[CHK / 256];
#pragma unroll
    for (int k = 0; k < CHK / 256; ++k) {
        int e = e0 + k * 256 + t;
        d[k] = (e < N_EDGES) ? dst[e] : -1;
        if (d[k] >= 0) atomicAdd(&h[d[k] >> 8], 1);
    }
    __syncthreads();
    for (int b = t; b < NBK; b += 256) {
        int v = h[b];
        base[b] = v ? atomicAdd(&bcur[b], v) : 0;
        h[b] = 0;
    }
    __syncthreads();
#pragma unroll
    for (int k = 0; k < CHK / 256; ++k) {
        if (d[k] < 0) continue;
        int e = e0 + k * 256 + t;
        int b = d[k] >> 8;
        int pos = base[b] + atomicAdd(&h[b], 1);
        unsigned ls = ((unsigned)(d[k] & 255) << 2) | (unsigned)etype[e];
        pairs[pos] = (unsigned)src[e] | (ls << 17);
    }
}

// per-bucket LDS counting sort: writes csr + cnt/offs (offs = segment END)
__global__ __launch_bounds__(256)
void sortseg_kernel(const unsigned* __restrict__ pairs, const int* __restrict__ ebase,
                    const int* __restrict__ bkcnt, int* __restrict__ csr,
                    int* __restrict__ cnt, int* __restrict__ offs) {
    __shared__ int hist[1024];
    __shared__ int sd[256];
    const int b = blockIdx.x;
    const int base = ebase[b];
    const int len  = bkcnt[b];
    const int t = threadIdx.x;
#pragma unroll
    for (int i = 0; i < 4; ++i) hist[t * 4 + i] = 0;
    __syncthreads();
    for (int i = t; i < len; i += 256)
        atomicAdd(&hist[pairs[base + i] >> 17], 1);
    __syncthreads();
    int c0 = hist[4 * t], c1 = hist[4 * t + 1], c2 = hist[4 * t + 2], c3 = hist[4 * t + 3];
    int run = c0 + c1 + c2 + c3;
    sd[t] = run;
    __syncthreads();
#pragma unroll
    for (int off = 1; off < 256; off <<= 1) {
        int a = (t >= off) ? sd[t - off] : 0;
        __syncthreads();
        sd[t] += a;
        __syncthreads();
    }
    int excl = sd[t] - run;
    int e0 = excl, e1 = excl + c0, e2 = excl + c0 + c1, e3 = excl + c0 + c1 + c2;
    hist[4 * t] = e0; hist[4 * t + 1] = e1; hist[4 * t + 2] = e2; hist[4 * t + 3] = e3;
    int seg0 = b * 1024 + 4 * t;
    if (seg0 < NR) {
        *(int4*)&cnt[seg0]  = int4{c0, c1, c2, c3};
        *(int4*)&offs[seg0] = int4{base + e0 + c0, base + e1 + c1,
                                   base + e2 + c2, base + e3 + c3};
    }
    __syncthreads();
    for (int i = t; i < len; i += 256) {
        unsigned p = pairs[base + i];
        int pos = atomicAdd(&hist[p >> 17], 1);   // LDS
        csr[base + pos] = (int)(p & 0x1FFFFu);
    }
}

// fused layer: gather (4 lanes/segment, 8-way ILP, packed fp16 accumulate)
// -> LDS A-tile -> MFMA -> h/pool. Tail lanes load the zero row (index N_NODES).
template<int DIN, int DOUT, bool RELU, bool POOL>
__global__ __launch_bounds__(256)
void layer_kernel(const _Float16* __restrict__ x,   // (N_NODES+1) rows
                  const int* __restrict__ csr,      // padded by >=8
                  const int* __restrict__ offsets,  // segment ENDs
                  const int* __restrict__ cnt,
                  const _Float16* __restrict__ Bt,  // [DOUT][SK]
                  const float* __restrict__ bias,   // [DOUT]
                  _Float16* __restrict__ hout,      // [(N+1), DOUT] if !POOL
                  const int* __restrict__ batch,
                  unsigned* __restrict__ pool) {
    constexpr int SK  = (DIN == 16) ? 96 : 160;
    constexpr int KP  = SK + 8;      // fp16 pad -> row stride mod-32-dw = 20
    constexpr int NPB = 16;
    constexpr int CPL = DIN / 4;     // fp16 channels per lane (4 or 8)
    constexpr int NP2 = CPL / 2;     // packed half2 per lane (2 or 4)
    constexpr int KS  = SK / 32;
    constexpr int ROWB = DIN * 2;    // row bytes (32 or 64)
    using VecT = typename std::conditional<CPL == 8, half8v, half4v>::type;

    __shared__ _Float16 sA[NPB][KP];
    __shared__ float pval[POOL ? NPB : 1][POOL ? 64 : 1];
    __shared__ int   pg[NPB];

    const int tid = threadIdx.x;

    // ---- gather into LDS ----
    {
        const int g    = tid >> 2;   // 0..63 segment group
        const int q    = tid & 3;
        const int nsub = g >> 2;
        const int r    = g & 3;
        const int n    = blockIdx.x * NPB + nsub;
        const int seg  = n * NUM_REL + r;
        const int len  = cnt[seg];
        const int start = offsets[seg] - len;
        const char* xb = (const char*)x;
        const int qoff = q * (ROWB / 4);

        half2v accA[NP2], accB[NP2];
#pragma unroll
        for (int p = 0; p < NP2; ++p) { accA[p] = half2v{0, 0}; accB[p] = half2v{0, 0}; }

        for (int k = 0; k < len; k += 8) {
            int lim = len - k;               // >= 1
            int c[8];
#pragma unroll
            for (int m = 0; m < 8; ++m)
                c[m] = csr[start + k + m];   // csr padded; tail redirected below
#pragma unroll
            for (int m = 0; m < 8; ++m)
                c[m] = (m < lim) ? c[m] : N_NODES;   // zero row
            VecT u[8];
#pragma unroll
            for (int m = 0; m < 8; ++m)
                u[m] = *(const VecT*)(xb + (c[m] * ROWB + qoff));
#pragma unroll
            for (int m = 0; m < 8; ++m) {
                const half2v* up = (const half2v*)&u[m];
#pragma unroll
                for (int p = 0; p < NP2; ++p) {
                    if (m & 1) accB[p] += up[p];
                    else       accA[p] += up[p];
                }
            }
        }
        float inv = 1.0f / fmaxf((float)len, 1.0f);
        VecT hv;
#pragma unroll
        for (int p = 0; p < NP2; ++p) {
            half2v s = accA[p] + accB[p];
            hv[2 * p]     = (_Float16)((float)s[0] * inv);
            hv[2 * p + 1] = (_Float16)((float)s[1] * inv);
        }
        *(VecT*)&sA[nsub][DIN + r * DIN + q * CPL] = hv;
        if (r == 0)
            *(VecT*)&sA[nsub][q * CPL] = *(const VecT*)(xb + (n * ROWB + qoff));
        if constexpr (SK > 5 * DIN) {
            // zero K-pad cols [5*DIN, SK) = 16 fp16
            if (r == 1 && q < 2)
                *(uint4*)&sA[nsub][5 * DIN + q * 8] = uint4{0, 0, 0, 0};
        }
        if constexpr (POOL) {
            if (tid < NPB) pg[tid] = batch[blockIdx.x * NPB + tid];
        }
    }
    __syncthreads();

    // ---- MFMA: wave w computes output j-tile w (16 cols) for all 16 rows ----
    const int w = tid >> 6, lane = tid & 63;
    const int lo16 = lane & 15, hi = lane >> 4;
    if (w * 16 < DOUT) {
        const int jt = w;
        f32x4 acc = f32x4{0.f, 0.f, 0.f, 0.f};
#pragma unroll
        for (int ks = 0; ks < KS; ++ks) {
            half8v a = *(const half8v*)&sA[lo16][ks * 32 + hi * 8];
            half8v b = *(const half8v*)&Bt[(size_t)(jt * 16 + lo16) * SK + ks * 32 + hi * 8];
            acc = __builtin_amdgcn_mfma_f32_16x16x32_f16(a, b, acc, 0, 0, 0);
        }
        float bj = bias[jt * 16 + lo16];
#pragma unroll
        for (int reg = 0; reg < 4; ++reg) {
            float v = acc[reg] + bj;
            if (RELU) v = fmaxf(v, 0.f);
            if constexpr (POOL) {
                pval[hi * 4 + reg][jt * 16 + lo16] = v;
            } else {
                hout[(size_t)(blockIdx.x * NPB + hi * 4 + reg) * DOUT + jt * 16 + lo16] = (_Float16)v;
            }
        }
    }

    // ---- fused max-pool over the block's 16 (sorted-batch) nodes ----
    if constexpr (POOL) {
        __syncthreads();
        if (tid < 64) {
            const int j = tid;
            float m = pval[0][j];
            int g0 = pg[0];
#pragma unroll
            for (int i = 1; i < NPB; ++i) {
                if (pg[i] == g0) {
                    m = fmaxf(m, pval[i][j]);
                } else {
                    atomicMax(pool + g0 * 64 + j, fenc(m));
                    g0 = pg[i];
                    m = pval[i][j];
                }
            }
            atomicMax(pool + g0 * 64 + j, fenc(m));
        }
    }
}

__global__ void decode_kernel(const unsigned* __restrict__ pool, float* __restrict__ out) {
    int i = blockIdx.x * blockDim.x + threadIdx.x;
    if (i < NUM_GRAPHS * 64) out[i] = fdec(pool[i]);
}

extern "C" void kernel_launch(void* const* d_in, const int* in_sizes, int n_in,
                              void* d_out, int out_size, void* d_ws, size_t ws_size,
                              hipStream_t stream) {
    const float* x     = (const float*)d_in[0];
    const int*   ei    = (const int*)d_in[1];
    const int*   etype = (const int*)d_in[2];
    const int*   batch = (const int*)d_in[3];
    const float* W1 = (const float*)d_in[4],  *root1 = (const float*)d_in[5],  *b1 = (const float*)d_in[6];
    const float* W2 = (const float*)d_in[7],  *root2 = (const float*)d_in[8],  *b2 = (const float*)d_in[9];
    const float* W3 = (const float*)d_in[10], *root3 = (const float*)d_in[11], *b3 = (const float*)d_in[12];
    float* out = (float*)d_out;

    const int* src = ei;
    const int* dst = ei + N_EDGES;

    // workspace layout (~30 MB), all sections 16B aligned; feature tables have
    // an extra zero row at index N_NODES (tail-lane target).
    int*       cnt   = (int*)d_ws;                     // NR
    int*       offs  = cnt + NR;                       // NR
    int*       bkcnt = offs + NR;                      // 512
    int*       ebase = bkcnt + 512;                    // 512
    int*       bcur  = ebase + 512;                    // 512
    int*       csr   = bcur + 512;                     // N_EDGES + 16 pad
    unsigned*  pairs = (unsigned*)(csr + N_EDGES + 16);// N_EDGES
    _Float16*  xh    = (_Float16*)(pairs + N_EDGES);   // (N+1)*16
    _Float16*  h1    = xh + (size_t)(N_NODES + 1) * 16;// (N+1)*16
    _Float16*  h2    = h1 + (size_t)(N_NODES + 1) * 16;// (N+1)*32
    _Float16*  Bt1   = h2 + (size_t)(N_NODES + 1) * 32;// 16*96
    _Float16*  Bt2   = Bt1 + 16 * 96;                  // 32*96
    _Float16*  Bt3   = Bt2 + 32 * 96;                  // 64*160
    unsigned*  pool  = (unsigned*)(Bt3 + 64 * 160);    // 256*64

    const int BT = 256;
    const int gL = N_NODES / 16;            // fused layer blocks

    prep_kernel<<<(N_NODES * 16 + BT - 1) / BT, BT, 0, stream>>>(
        x, xh, W1, root1, Bt1, W2, root2, Bt2, W3, root3, Bt3, bkcnt, pool, h1, h2);

    cbuck_kernel<<<NCH, BT, 0, stream>>>(dst, bkcnt);
    scanE_kernel<<<1, BT, 0, stream>>>(bkcnt, ebase, bcur);
    bin_kernel<<<NCH, BT, 0, stream>>>(src, dst, etype, bcur, pairs);
    sortseg_kernel<<<NBK, BT, 0, stream>>>(pairs, ebase, bkcnt, csr, cnt, offs);

    layer_kernel<16, 16, true,  false><<<gL, BT, 0, stream>>>(
        xh, csr, offs, cnt, Bt1, b1, h1, batch, pool);
    layer_kernel<16, 32, true,  false><<<gL, BT, 0, stream>>>(
        h1, csr, offs, cnt, Bt2, b2, h2, batch, pool);
    layer_kernel<32, 64, false, true ><<<gL, BT, 0, stream>>>(
        h2, csr, offs, cnt, Bt3, b3, nullptr, batch, pool);

    decode_kernel<<<(NUM_GRAPHS * 64 + BT - 1) / BT, BT, 0, stream>>>(pool, out);
}

// Round 13
// 120.466 us; speedup vs baseline: 3.0813x; 1.0917x over previous
//
#include <hip/hip_runtime.h>
#include <type_traits>

#define N_NODES    100000
#define N_EDGES    1600000
#define NUM_REL    4
#define NUM_GRAPHS 256

constexpr int NR   = N_NODES * NUM_REL;         // 400000 segments
constexpr int NBK  = (N_NODES + 255) / 256;     // 391 buckets of 256 nodes (1024 segments)
constexpr int CAP  = 6144;                      // slots per bucket (mean 4092, sigma 64)
constexpr int CHK  = 8192;                      // edges per binning block
constexpr int NCH  = (N_EDGES + CHK - 1) / CHK; // 196 chunks

typedef _Float16 half2v __attribute__((ext_vector_type(2)));
typedef _Float16 half4v __attribute__((ext_vector_type(4)));
typedef _Float16 half8v __attribute__((ext_vector_type(8)));
typedef float    f32x4  __attribute__((ext_vector_type(4)));

// ---- monotonic float<->uint encoding for atomicMax on floats ----
__device__ __forceinline__ unsigned fenc(float f) {
    unsigned u = __float_as_uint(f);
    return (u & 0x80000000u) ? ~u : (u | 0x80000000u);
}
__device__ __forceinline__ float fdec(unsigned e) {
    return __uint_as_float((e & 0x80000000u) ? (e ^ 0x80000000u) : ~e);
}

__device__ __forceinline__ void bstack_fill(const float* __restrict__ W,
                                            const float* __restrict__ root,
                                            _Float16* __restrict__ Bt,
                                            int i, int DIN, int DOUT, int SK) {
    int j = i / SK, kk = i % SK;
    float v = (kk < DIN) ? root[kk * DOUT + j]
            : (kk < 5 * DIN) ? W[(kk - DIN) * DOUT + j] : 0.f;
    Bt[j * SK + kk] = (_Float16)v;
}

// fused prep: bucket cursors, pool init, fp16-convert x, zero-rows, weight stacks
__global__ void prep_kernel(const float* __restrict__ x, _Float16* __restrict__ xh,
                            const float* __restrict__ W1, const float* __restrict__ root1, _Float16* __restrict__ Bt1,
                            const float* __restrict__ W2, const float* __restrict__ root2, _Float16* __restrict__ Bt2,
                            const float* __restrict__ W3, const float* __restrict__ root3, _Float16* __restrict__ Bt3,
                            int* __restrict__ bcur, unsigned* __restrict__ pool,
                            _Float16* __restrict__ h1, _Float16* __restrict__ h2) {
    int i = blockIdx.x * 256 + threadIdx.x;
    if (i < N_NODES * 16) xh[i] = (_Float16)x[i];
    if (i < 512) bcur[i] = i * CAP;
    if (i < NUM_GRAPHS * 64) pool[i] = fenc(-INFINITY);
    if (i < 16 * 96)  bstack_fill(W1, root1, Bt1, i, 16, 16, 96);
    if (i < 32 * 96)  bstack_fill(W2, root2, Bt2, i, 16, 32, 96);
    if (i < 64 * 160) bstack_fill(W3, root3, Bt3, i, 32, 64, 160);
    // zero row N of each feature table (tail-lane target)
    if (i < 16) xh[(size_t)N_NODES * 16 + i] = (_Float16)0.f;
    if (i < 16) h1[(size_t)N_NODES * 16 + i] = (_Float16)0.f;
    if (i < 32) h2[(size_t)N_NODES * 32 + i] = (_Float16)0.f;
}

// partition edges into per-bucket regions (base = b*CAP): (localseg<<17) | src
__global__ __launch_bounds__(256)
void bin_kernel(const int* __restrict__ src, const int* __restrict__ dst,
                const int* __restrict__ etype, int* __restrict__ bcur,
                unsigned* __restrict__ pairs) {
    __shared__ int h[512];
    __shared__ int base[512];
    const int t = threadIdx.x;
    h[t] = 0; h[t + 256] = 0;
    __syncthreads();
    const int e0 = blockIdx.x * CHK;
    int d[CHK / 256];
#pragma unroll
    for (int k = 0; k < CHK / 256; ++k) {
        int e = e0 + k * 256 + t;
        d[k] = (e < N_EDGES) ? dst[e] : -1;
        if (d[k] >= 0) atomicAdd(&h[d[k] >> 8], 1);
    }
    __syncthreads();
    for (int b = t; b < NBK; b += 256) {
        int v = h[b];
        base[b] = v ? atomicAdd(&bcur[b], v) : 0;
        h[b] = 0;
    }
    __syncthreads();
#pragma unroll
    for (int k = 0; k < CHK / 256; ++k) {
        if (d[k] < 0) continue;
        int e = e0 + k * 256 + t;
        int b = d[k] >> 8;
        int pos = base[b] + atomicAdd(&h[b], 1);
        if (pos < (b + 1) * CAP) {            // capacity guard (unreachable: 32 sigma)
            unsigned ls = ((unsigned)(d[k] & 255) << 2) | (unsigned)etype[e];
            pairs[pos] = (unsigned)src[e] | (ls << 17);
        }
    }
}

// per-bucket LDS counting sort: csr (padded layout) + seginfo {cnt, end}
__global__ __launch_bounds__(256)
void sortseg_kernel(const unsigned* __restrict__ pairs, const int* __restrict__ bcur,
                    int* __restrict__ csr, int2* __restrict__ seginfo) {
    __shared__ int hist[1024];
    __shared__ int sd[256];
    const int b = blockIdx.x;
    const int base = b * CAP;
    const int len  = bcur[b] - base;
    const int t = threadIdx.x;
#pragma unroll
    for (int i = 0; i < 4; ++i) hist[t * 4 + i] = 0;
    __syncthreads();
    for (int i = t; i < len; i += 256)
        atomicAdd(&hist[pairs[base + i] >> 17], 1);
    __syncthreads();
    int c0 = hist[4 * t], c1 = hist[4 * t + 1], c2 = hist[4 * t + 2], c3 = hist[4 * t + 3];
    int run = c0 + c1 + c2 + c3;
    sd[t] = run;
    __syncthreads();
#pragma unroll
    for (int off = 1; off < 256; off <<= 1) {
        int a = (t >= off) ? sd[t - off] : 0;
        __syncthreads();
        sd[t] += a;
        __syncthreads();
    }
    int excl = sd[t] - run;
    int e0 = excl, e1 = excl + c0, e2 = excl + c0 + c1, e3 = excl + c0 + c1 + c2;
    hist[4 * t] = e0; hist[4 * t + 1] = e1; hist[4 * t + 2] = e2; hist[4 * t + 3] = e3;
    int seg0 = b * 1024 + 4 * t;
    if (seg0 < NR) {   // NR % 4 == 0
        *(int4*)&seginfo[seg0]     = int4{c0, base + e0 + c0, c1, base + e1 + c1};
        *(int4*)&seginfo[seg0 + 2] = int4{c2, base + e2 + c2, c3, base + e3 + c3};
    }
    __syncthreads();
    for (int i = t; i < len; i += 256) {
        unsigned p = pairs[base + i];
        int pos = atomicAdd(&hist[p >> 17], 1);   // LDS
        csr[base + pos] = (int)(p & 0x1FFFFu);
    }
}

// fused layer: gather (4 lanes/segment, 8-way ILP, packed fp16 accumulate)
// -> LDS A-tile -> MFMA -> h/pool. Tail lanes load the zero row (index N_NODES).
template<int DIN, int DOUT, bool RELU, bool POOL>
__global__ __launch_bounds__(256)
void layer_kernel(const _Float16* __restrict__ x,   // (N_NODES+1) rows
                  const int* __restrict__ csr,      // padded region layout
                  const int2* __restrict__ seginfo, // {cnt, end}
                  const _Float16* __restrict__ Bt,  // [DOUT][SK]
                  const float* __restrict__ bias,   // [DOUT]
                  _Float16* __restrict__ hout,      // [(N+1), DOUT] if !POOL
                  const int* __restrict__ batch,
                  unsigned* __restrict__ pool) {
    constexpr int SK  = (DIN == 16) ? 96 : 160;
    constexpr int KP  = SK + 8;
    constexpr int NPB = 16;
    constexpr int CPL = DIN / 4;
    constexpr int NP2 = CPL / 2;
    constexpr int KS  = SK / 32;
    constexpr int ROWB = DIN * 2;
    using VecT = typename std::conditional<CPL == 8, half8v, half4v>::type;

    __shared__ _Float16 sA[NPB][KP];
    __shared__ float pval[POOL ? NPB : 1][POOL ? 64 : 1];
    __shared__ int   pg[NPB];

    const int tid = threadIdx.x;

    // ---- gather into LDS ----
    {
        const int g    = tid >> 2;
        const int q    = tid & 3;
        const int nsub = g >> 2;
        const int r    = g & 3;
        const int n    = blockIdx.x * NPB + nsub;
        const int seg  = n * NUM_REL + r;
        const int2 si  = seginfo[seg];
        const int len  = si.x;
        const int start = si.y - len;
        const char* xb = (const char*)x;
        const int qoff = q * (ROWB / 4);

        half2v accA[NP2], accB[NP2];
#pragma unroll
        for (int p = 0; p < NP2; ++p) { accA[p] = half2v{0, 0}; accB[p] = half2v{0, 0}; }

        for (int k = 0; k < len; k += 8) {
            int lim = len - k;               // >= 1
            int c[8];
#pragma unroll
            for (int m = 0; m < 8; ++m)
                c[m] = csr[start + k + m];   // csr padded; tail redirected below
#pragma unroll
            for (int m = 0; m < 8; ++m)
                c[m] = (m < lim) ? c[m] : N_NODES;   // zero row
            VecT u[8];
#pragma unroll
            for (int m = 0; m < 8; ++m)
                u[m] = *(const VecT*)(xb + (c[m] * ROWB + qoff));
#pragma unroll
            for (int m = 0; m < 8; ++m) {
                const half2v* up = (const half2v*)&u[m];
#pragma unroll
                for (int p = 0; p < NP2; ++p) {
                    if (m & 1) accB[p] += up[p];
                    else       accA[p] += up[p];
                }
            }
        }
        float inv = 1.0f / fmaxf((float)len, 1.0f);
        VecT hv;
#pragma unroll
        for (int p = 0; p < NP2; ++p) {
            half2v s = accA[p] + accB[p];
            hv[2 * p]     = (_Float16)((float)s[0] * inv);
            hv[2 * p + 1] = (_Float16)((float)s[1] * inv);
        }
        *(VecT*)&sA[nsub][DIN + r * DIN + q * CPL] = hv;
        if (r == 0)
            *(VecT*)&sA[nsub][q * CPL] = *(const VecT*)(xb + (n * ROWB + qoff));
        if constexpr (SK > 5 * DIN) {
            if (r == 1 && q < 2)
                *(uint4*)&sA[nsub][5 * DIN + q * 8] = uint4{0, 0, 0, 0};
        }
        if constexpr (POOL) {
            if (tid < NPB) pg[tid] = batch[blockIdx.x * NPB + tid];
        }
    }
    __syncthreads();

    // ---- MFMA: wave w computes output j-tile w (16 cols) for all 16 rows ----
    const int w = tid >> 6, lane = tid & 63;
    const int lo16 = lane & 15, hi = lane >> 4;
    if (w * 16 < DOUT) {
        const int jt = w;
        f32x4 acc = f32x4{0.f, 0.f, 0.f, 0.f};
#pragma unroll
        for (int ks = 0; ks < KS; ++ks) {
            half8v a = *(const half8v*)&sA[lo16][ks * 32 + hi * 8];
            half8v b = *(const half8v*)&Bt[(size_t)(jt * 16 + lo16) * SK + ks * 32 + hi * 8];
            acc = __builtin_amdgcn_mfma_f32_16x16x32_f16(a, b, acc, 0, 0, 0);
        }
        float bj = bias[jt * 16 + lo16];
#pragma unroll
        for (int reg = 0; reg < 4; ++reg) {
            float v = acc[reg] + bj;
            if (RELU) v = fmaxf(v, 0.f);
            if constexpr (POOL) {
                pval[hi * 4 + reg][jt * 16 + lo16] = v;
            } else {
                hout[(size_t)(blockIdx.x * NPB + hi * 4 + reg) * DOUT + jt * 16 + lo16] = (_Float16)v;
            }
        }
    }

    // ---- fused max-pool over the block's 16 (sorted-batch) nodes ----
    if constexpr (POOL) {
        __syncthreads();
        if (tid < 64) {
            const int j = tid;
            float m = pval[0][j];
            int g0 = pg[0];
#pragma unroll
            for (int i = 1; i < NPB; ++i) {
                if (pg[i] == g0) {
                    m = fmaxf(m, pval[i][j]);
                } else {
                    atomicMax(pool + g0 * 64 + j, fenc(m));
                    g0 = pg[i];
                    m = pval[i][j];
                }
            }
            atomicMax(pool + g0 * 64 + j, fenc(m));
        }
    }
}

__global__ void decode_kernel(const unsigned* __restrict__ pool, float* __restrict__ out) {
    int i = blockIdx.x * blockDim.x + threadIdx.x;
    if (i < NUM_GRAPHS * 64) out[i] = fdec(pool[i]);
}

extern "C" void kernel_launch(void* const* d_in, const int* in_sizes, int n_in,
                              void* d_out, int out_size, void* d_ws, size_t ws_size,
                              hipStream_t stream) {
    const float* x     = (const float*)d_in[0];
    const int*   ei    = (const int*)d_in[1];
    const int*   etype = (const int*)d_in[2];
    const int*   batch = (const int*)d_in[3];
    const float* W1 = (const float*)d_in[4],  *root1 = (const float*)d_in[5],  *b1 = (const float*)d_in[6];
    const float* W2 = (const float*)d_in[7],  *root2 = (const float*)d_in[8],  *b2 = (const float*)d_in[9];
    const float* W3 = (const float*)d_in[10], *root3 = (const float*)d_in[11], *b3 = (const float*)d_in[12];
    float* out = (float*)d_out;

    const int* src = ei;
    const int* dst = ei + N_EDGES;

    // workspace layout (~40 MB), all sections 16B aligned
    int2*      seginfo = (int2*)d_ws;                       // NR {cnt, end}
    int*       bcur    = (int*)(seginfo + NR);              // 512
    int*       csr     = bcur + 512;                        // NBK*CAP + 16 pad
    unsigned*  pairs   = (unsigned*)(csr + NBK * CAP + 16); // NBK*CAP
    _Float16*  xh      = (_Float16*)(pairs + NBK * CAP);    // (N+1)*16
    _Float16*  h1      = xh + (size_t)(N_NODES + 1) * 16;   // (N+1)*16
    _Float16*  h2      = h1 + (size_t)(N_NODES + 1) * 16;   // (N+1)*32
    _Float16*  Bt1     = h2 + (size_t)(N_NODES + 1) * 32;   // 16*96
    _Float16*  Bt2     = Bt1 + 16 * 96;                     // 32*96
    _Float16*  Bt3     = Bt2 + 32 * 96;                     // 64*160
    unsigned*  pool    = (unsigned*)(Bt3 + 64 * 160);       // 256*64

    const int BT = 256;
    const int gL = N_NODES / 16;            // fused layer blocks

    prep_kernel<<<(N_NODES * 16 + BT - 1) / BT, BT, 0, stream>>>(
        x, xh, W1, root1, Bt1, W2, root2, Bt2, W3, root3, Bt3, bcur, pool, h1, h2);

    bin_kernel<<<NCH, BT, 0, stream>>>(src, dst, etype, bcur, pairs);
    sortseg_kernel<<<NBK, BT, 0, stream>>>(pairs, bcur, csr, seginfo);

    layer_kernel<16, 16, true,  false><<<gL, BT, 0, stream>>>(
        xh, csr, seginfo, Bt1, b1, h1, batch, pool);
    layer_kernel<16, 32, true,  false><<<gL, BT, 0, stream>>>(
        h1, csr, seginfo, Bt2, b2, h2, batch, pool);
    layer_kernel<32, 64, false, true ><<<gL, BT, 0, stream>>>(
        h2, csr, seginfo, Bt3, b3, nullptr, batch, pool);

    decode_kernel<<<(NUM_GRAPHS * 64 + BT - 1) / BT, BT, 0, stream>>>(pool, out);
}